// Round 1
// baseline (4472.655 us; speedup 1.0000x reference)
//
#include <hip/hip_runtime.h>

// Problem constants
#define BB   4
#define SS   2048
#define DDIM 1024
#define HH   16
#define DKK  64
#define FFF  2048
#define NTOK (BB * SS)   // 8192

typedef __bf16 bf16x8 __attribute__((ext_vector_type(8)));
typedef float floatx4 __attribute__((ext_vector_type(4)));

__device__ __forceinline__ unsigned short f2bf(float f) {
    union { float f; unsigned u; } v; v.f = f;
    unsigned r = v.u + 0x7fffu + ((v.u >> 16) & 1u);   // RNE
    return (unsigned short)(r >> 16);
}
__device__ __forceinline__ float bf2f(unsigned short h) {
    union { unsigned u; float f; } v; v.u = ((unsigned)h) << 16;
    return v.f;
}

// ---------------------------------------------------------------------------
// Transpose fp32 W[K][N] -> bf16 Wt[N][K]  (so GEMM reads B^T contiguously)
// ---------------------------------------------------------------------------
__global__ __launch_bounds__(256) void transpose_to_bf16(
    const float* __restrict__ W, unsigned short* __restrict__ Wt, int K, int N) {
    __shared__ float tile[64][65];
    int k0 = blockIdx.x * 64, n0 = blockIdx.y * 64;
    int tid = threadIdx.x;
#pragma unroll
    for (int i = 0; i < 16; ++i) {
        int e = i * 256 + tid;
        int r = e >> 6, c = e & 63;           // r: k-offset, c: n-offset
        tile[r][c] = W[(size_t)(k0 + r) * N + (n0 + c)];
    }
    __syncthreads();
#pragma unroll
    for (int i = 0; i < 16; ++i) {
        int e = i * 256 + tid;
        int r = e >> 6, c = e & 63;           // r: n-offset, c: k-offset
        Wt[(size_t)(n0 + r) * K + (k0 + c)] = f2bf(tile[c][r]);
    }
}

// ---------------------------------------------------------------------------
// LayerNorm: fp32 in -> bf16 out, one block per row (D=1024, 256 thr x 4)
// ---------------------------------------------------------------------------
__device__ __forceinline__ float block_sum256(float s) {
#pragma unroll
    for (int o = 32; o > 0; o >>= 1) s += __shfl_xor(s, o);
    __shared__ float partial[4];
    int w = threadIdx.x >> 6;
    __syncthreads();                           // protect reuse across calls
    if ((threadIdx.x & 63) == 0) partial[w] = s;
    __syncthreads();
    return partial[0] + partial[1] + partial[2] + partial[3];
}

__global__ __launch_bounds__(256) void layernorm_bf16(
    const float* __restrict__ x, const float* __restrict__ g,
    const float* __restrict__ b, unsigned short* __restrict__ out, float eps) {
    size_t row = blockIdx.x;
    const float* xr = x + row * DDIM;
    int tid = threadIdx.x;
    float4 v = *(const float4*)(xr + tid * 4);
    float mu = block_sum256(v.x + v.y + v.z + v.w) * (1.0f / DDIM);
    float dx = v.x - mu, dy = v.y - mu, dz = v.z - mu, dw = v.w - mu;
    float var = block_sum256(dx * dx + dy * dy + dz * dz + dw * dw) * (1.0f / DDIM);
    float rstd = rsqrtf(var + eps);
    int c = tid * 4;
    unsigned short* o = out + row * DDIM + c;
    o[0] = f2bf(dx * rstd * g[c + 0] + b[c + 0]);
    o[1] = f2bf(dy * rstd * g[c + 1] + b[c + 1]);
    o[2] = f2bf(dz * rstd * g[c + 2] + b[c + 2]);
    o[3] = f2bf(dw * rstd * g[c + 3] + b[c + 3]);
}

// ---------------------------------------------------------------------------
// bf16 MFMA GEMM, C = A[MxK] @ B (given as Bt[NxK]) + bias + resid, opt ReLU
// 64x64 tile, BK=32, 4 waves: wave w -> rows 16w..16w+15, 4 n-tiles of 16.
// m92-verified layouts: A-frag lane&15=m, k=quad*8+j ; C/D row=quad*4+r.
// ---------------------------------------------------------------------------
__global__ __launch_bounds__(256) void gemm_bt(
    const unsigned short* __restrict__ A, const unsigned short* __restrict__ Bt,
    const float* __restrict__ bias, const float* __restrict__ resid,
    float* __restrict__ outf, unsigned short* __restrict__ outh,
    int M, int N, int K, int relu) {
    __shared__ unsigned short As[64][32];
    __shared__ unsigned short Bs[64][32];
    int tid = threadIdx.x;
    int wave = tid >> 6, lane = tid & 63;
    int lr = lane & 15, quad = lane >> 4;
    int m0 = blockIdx.x * 64, n0 = blockIdx.y * 64;
    int arow = tid >> 2, acol = (tid & 3) * 8;   // 256 thr x 8 bf16 = 64x32 tile

    floatx4 acc[4];
#pragma unroll
    for (int t = 0; t < 4; ++t)
#pragma unroll
        for (int r = 0; r < 4; ++r) acc[t][r] = 0.0f;

    const size_t a_base = (size_t)(m0 + arow) * K + acol;
    const size_t b_base = (size_t)(n0 + arow) * K + acol;

    for (int k0 = 0; k0 < K; k0 += 32) {
        *(float4*)(&As[arow][acol]) = *(const float4*)(A + a_base + k0);
        *(float4*)(&Bs[arow][acol]) = *(const float4*)(Bt + b_base + k0);
        __syncthreads();
        bf16x8 af = *(const bf16x8*)(&As[16 * wave + lr][quad * 8]);
#pragma unroll
        for (int t = 0; t < 4; ++t) {
            bf16x8 bf = *(const bf16x8*)(&Bs[16 * t + lr][quad * 8]);
            acc[t] = __builtin_amdgcn_mfma_f32_16x16x32_bf16(af, bf, acc[t], 0, 0, 0);
        }
        __syncthreads();
    }

#pragma unroll
    for (int t = 0; t < 4; ++t) {
        int col = n0 + 16 * t + lr;
#pragma unroll
        for (int r = 0; r < 4; ++r) {
            int row = m0 + 16 * wave + quad * 4 + r;
            float v = acc[t][r];
            if (bias)  v += bias[col];
            if (resid) v += resid[(size_t)row * N + col];
            if (relu)  v = fmaxf(v, 0.0f);
            size_t idx = (size_t)row * N + col;
            if (outf) outf[idx] = v;
            else      outh[idx] = f2bf(v);
        }
    }
}

// ---------------------------------------------------------------------------
// Attention (vector version, round 0): one block = (b, h, 4 q-rows).
// Scores for 4 rows materialized in LDS (4x2048 fp32), K/V tiles staged with
// padded stride 65 (bank = (j+d)%32, 2-way aliasing = free).
// ---------------------------------------------------------------------------
__global__ __launch_bounds__(256) void attention_kernel(
    const unsigned short* __restrict__ q, const unsigned short* __restrict__ k,
    const unsigned short* __restrict__ v, unsigned short* __restrict__ ctx) {
    __shared__ float qlds[4][64];
    __shared__ float sc[4][SS];
    __shared__ float kt[64][65];
    __shared__ float inv_l[4];

    int tid = threadIdx.x;
    int bid = blockIdx.x;
    int qc = bid & 511;                 // S/4 = 512 q-chunks
    int h  = (bid >> 9) & 15;
    int b  = bid >> 13;
    size_t rowbase = (size_t)b * SS;
    int q0 = qc * 4;
    int colh = h * 64;

    {   // load 4 q-rows, pre-scaled by 1/sqrt(DK)=1/8
        int r = tid >> 6, d = tid & 63;
        qlds[r][d] = bf2f(q[(rowbase + q0 + r) * DDIM + colh + d]) * 0.125f;
    }
    __syncthreads();

    int qi = tid >> 6;                  // wave id = q-row 0..3
    int jl = tid & 63;

    // ---- pass 1: scores ----
    for (int jt = 0; jt < SS / 64; ++jt) {
#pragma unroll
        for (int i = 0; i < 2; ++i) {   // stage 64x64 bf16 tile, 16B loads
            int e = i * 256 + tid;
            int r = e >> 3, c8 = (e & 7) * 8;
            uint4 raw = *(const uint4*)(k + (rowbase + jt * 64 + r) * DDIM + colh + c8);
            const unsigned short* ph = (const unsigned short*)&raw;
#pragma unroll
            for (int j = 0; j < 8; ++j) kt[r][c8 + j] = bf2f(ph[j]);
        }
        __syncthreads();
        float s = 0.f;
#pragma unroll
        for (int d = 0; d < 64; ++d) s += qlds[qi][d] * kt[jl][d];
        sc[qi][jt * 64 + jl] = s;
        __syncthreads();
    }

    // ---- pass 2: softmax (wave-local: wave qi owns row qi) ----
    {
        float m = -1e30f;
        for (int i = 0; i < SS / 64; ++i) m = fmaxf(m, sc[qi][jl + 64 * i]);
#pragma unroll
        for (int o = 32; o > 0; o >>= 1) m = fmaxf(m, __shfl_xor(m, o));
        float sum = 0.f;
        for (int i = 0; i < SS / 64; ++i) {
            float e = __expf(sc[qi][jl + 64 * i] - m);
            sc[qi][jl + 64 * i] = e;
            sum += e;
        }
#pragma unroll
        for (int o = 32; o > 0; o >>= 1) sum += __shfl_xor(sum, o);
        if (jl == 0) inv_l[qi] = 1.0f / sum;
    }
    __syncthreads();

    // ---- pass 3: P @ V ----
    float acc = 0.f;
    for (int jt = 0; jt < SS / 64; ++jt) {
#pragma unroll
        for (int i = 0; i < 2; ++i) {
            int e = i * 256 + tid;
            int r = e >> 3, c8 = (e & 7) * 8;
            uint4 raw = *(const uint4*)(v + (rowbase + jt * 64 + r) * DDIM + colh + c8);
            const unsigned short* ph = (const unsigned short*)&raw;
#pragma unroll
            for (int j = 0; j < 8; ++j) kt[r][c8 + j] = bf2f(ph[j]);
        }
        __syncthreads();
#pragma unroll
        for (int jj = 0; jj < 64; ++jj) acc += sc[qi][jt * 64 + jj] * kt[jj][jl];
        __syncthreads();
    }
    ctx[(rowbase + q0 + qi) * DDIM + colh + jl] = f2bf(acc * inv_l[qi]);
}

// ---------------------------------------------------------------------------
extern "C" void kernel_launch(void* const* d_in, const int* in_sizes, int n_in,
                              void* d_out, int out_size, void* d_ws, size_t ws_size,
                              hipStream_t stream) {
    const float* x     = (const float*)d_in[0];
    const float* Wq    = (const float*)d_in[1];
    const float* Wk    = (const float*)d_in[2];
    const float* Wv    = (const float*)d_in[3];
    const float* Wo    = (const float*)d_in[4];
    const float* ln1g  = (const float*)d_in[5];
    const float* ln1b  = (const float*)d_in[6];
    const float* fc1w  = (const float*)d_in[7];
    const float* fc1b  = (const float*)d_in[8];
    const float* fc2w  = (const float*)d_in[9];
    const float* fc2b  = (const float*)d_in[10];
    const float* ln2g  = (const float*)d_in[11];
    const float* ln2b  = (const float*)d_in[12];
    float* out = (float*)d_out;

    // workspace layout (bf16 = unsigned short), all regions 16B-aligned
    char* ws = (char*)d_ws;
    const size_t MB = 1024 * 1024;
    unsigned short* wqT  = (unsigned short*)(ws + 0 * MB);   // 1024x1024  (2MB)
    unsigned short* wkT  = (unsigned short*)(ws + 2 * MB);
    unsigned short* wvT  = (unsigned short*)(ws + 4 * MB);
    unsigned short* woT  = (unsigned short*)(ws + 6 * MB);
    unsigned short* fc1T = (unsigned short*)(ws + 8 * MB);   // 2048x1024  (4MB)
    unsigned short* fc2T = (unsigned short*)(ws + 12 * MB);  // 1024x2048  (4MB)
    unsigned short* xn   = (unsigned short*)(ws + 16 * MB);  // 8192x1024  (16MB) / reused as ctx
    unsigned short* qb   = (unsigned short*)(ws + 32 * MB);  // 8192x1024  (16MB) / reused as hn
    unsigned short* kb   = (unsigned short*)(ws + 48 * MB);  // 8192x1024  (16MB)
    unsigned short* vb   = (unsigned short*)(ws + 64 * MB);  // 8192x1024  (16MB)
    unsigned short* ctx = xn;                                 // reuse
    unsigned short* hn  = qb;                                 // reuse
    unsigned short* h1  = kb;                                 // 8192x2048 (32MB) over kb+vb

    dim3 blk(256);

    // 1) weight conversion/transpose
    transpose_to_bf16<<<dim3(16, 16), blk, 0, stream>>>(Wq, wqT, 1024, 1024);
    transpose_to_bf16<<<dim3(16, 16), blk, 0, stream>>>(Wk, wkT, 1024, 1024);
    transpose_to_bf16<<<dim3(16, 16), blk, 0, stream>>>(Wv, wvT, 1024, 1024);
    transpose_to_bf16<<<dim3(16, 16), blk, 0, stream>>>(Wo, woT, 1024, 1024);
    transpose_to_bf16<<<dim3(16, 32), blk, 0, stream>>>(fc1w, fc1T, 1024, 2048);
    transpose_to_bf16<<<dim3(32, 16), blk, 0, stream>>>(fc2w, fc2T, 2048, 1024);

    // 2) LN1
    layernorm_bf16<<<NTOK, blk, 0, stream>>>(x, ln1g, ln1b, xn, 1e-5f);

    // 3) Q, K, V projections
    gemm_bt<<<dim3(128, 16), blk, 0, stream>>>(xn, wqT, nullptr, nullptr, nullptr, qb, NTOK, 1024, 1024, 0);
    gemm_bt<<<dim3(128, 16), blk, 0, stream>>>(xn, wkT, nullptr, nullptr, nullptr, kb, NTOK, 1024, 1024, 0);
    gemm_bt<<<dim3(128, 16), blk, 0, stream>>>(xn, wvT, nullptr, nullptr, nullptr, vb, NTOK, 1024, 1024, 0);

    // 4) attention  (B*H*S/4 = 32768 blocks)
    attention_kernel<<<32768, blk, 0, stream>>>(qb, kb, vb, ctx);

    // 5) out = ctx @ Wo + x   (fp32 into d_out)
    gemm_bt<<<dim3(128, 16), blk, 0, stream>>>(ctx, woT, nullptr, x, out, nullptr, NTOK, 1024, 1024, 0);

    // 6) LN2 (eps=1e-6)
    layernorm_bf16<<<NTOK, blk, 0, stream>>>(out, ln2g, ln2b, hn, 1e-6f);

    // 7) h1 = relu(hn @ fc1 + b1)
    gemm_bt<<<dim3(128, 32), blk, 0, stream>>>(hn, fc1T, fc1b, nullptr, nullptr, h1, NTOK, 2048, 1024, 1);

    // 8) final = out + h1 @ fc2 + b2  (in-place residual on d_out)
    gemm_bt<<<dim3(128, 16), blk, 0, stream>>>(h1, fc2T, fc2b, out, out, nullptr, NTOK, 1024, 2048, 0);
}

// Round 2
// 698.579 us; speedup vs baseline: 6.4025x; 6.4025x over previous
//
#include <hip/hip_runtime.h>

// Problem constants
#define BB   4
#define SS   2048
#define DDIM 1024
#define HH   16
#define DKK  64
#define FFF  2048
#define NTOK (BB * SS)   // 8192

typedef __bf16 bf16x8 __attribute__((ext_vector_type(8)));
typedef float floatx4 __attribute__((ext_vector_type(4)));

__device__ __forceinline__ unsigned short f2bf(float f) {
    union { float f; unsigned u; } v; v.f = f;
    unsigned r = v.u + 0x7fffu + ((v.u >> 16) & 1u);   // RNE
    return (unsigned short)(r >> 16);
}
__device__ __forceinline__ float bf2f(unsigned short h) {
    union { unsigned u; float f; } v; v.u = ((unsigned)h) << 16;
    return v.f;
}

// ---------------------------------------------------------------------------
// Transpose fp32 W[K][N] -> bf16 Wt[N][K]  (so GEMM reads B^T contiguously)
// ---------------------------------------------------------------------------
__global__ __launch_bounds__(256) void transpose_to_bf16(
    const float* __restrict__ W, unsigned short* __restrict__ Wt, int K, int N) {
    __shared__ float tile[64][65];
    int k0 = blockIdx.x * 64, n0 = blockIdx.y * 64;
    int tid = threadIdx.x;
#pragma unroll
    for (int i = 0; i < 16; ++i) {
        int e = i * 256 + tid;
        int r = e >> 6, c = e & 63;
        tile[r][c] = W[(size_t)(k0 + r) * N + (n0 + c)];
    }
    __syncthreads();
#pragma unroll
    for (int i = 0; i < 16; ++i) {
        int e = i * 256 + tid;
        int r = e >> 6, c = e & 63;
        Wt[(size_t)(n0 + r) * K + (k0 + c)] = f2bf(tile[c][r]);
    }
}

// ---------------------------------------------------------------------------
// LayerNorm: fp32 in -> bf16 out, one block per row (D=1024, 256 thr x 4)
// ---------------------------------------------------------------------------
__device__ __forceinline__ float block_sum256(float s) {
#pragma unroll
    for (int o = 32; o > 0; o >>= 1) s += __shfl_xor(s, o);
    __shared__ float partial[4];
    int w = threadIdx.x >> 6;
    __syncthreads();
    if ((threadIdx.x & 63) == 0) partial[w] = s;
    __syncthreads();
    return partial[0] + partial[1] + partial[2] + partial[3];
}

__global__ __launch_bounds__(256) void layernorm_bf16(
    const float* __restrict__ x, const float* __restrict__ g,
    const float* __restrict__ b, unsigned short* __restrict__ out, float eps) {
    size_t row = blockIdx.x;
    const float* xr = x + row * DDIM;
    int tid = threadIdx.x;
    float4 v = *(const float4*)(xr + tid * 4);
    float mu = block_sum256(v.x + v.y + v.z + v.w) * (1.0f / DDIM);
    float dx = v.x - mu, dy = v.y - mu, dz = v.z - mu, dw = v.w - mu;
    float var = block_sum256(dx * dx + dy * dy + dz * dz + dw * dw) * (1.0f / DDIM);
    float rstd = rsqrtf(var + eps);
    int c = tid * 4;
    unsigned short* o = out + row * DDIM + c;
    o[0] = f2bf(dx * rstd * g[c + 0] + b[c + 0]);
    o[1] = f2bf(dy * rstd * g[c + 1] + b[c + 1]);
    o[2] = f2bf(dz * rstd * g[c + 2] + b[c + 2]);
    o[3] = f2bf(dw * rstd * g[c + 3] + b[c + 3]);
}

// ---------------------------------------------------------------------------
// bf16 MFMA GEMM, C = A[MxK] @ B (given as Bt[NxK]) + bias + resid, opt ReLU
// ---------------------------------------------------------------------------
__global__ __launch_bounds__(256) void gemm_bt(
    const unsigned short* __restrict__ A, const unsigned short* __restrict__ Bt,
    const float* __restrict__ bias, const float* __restrict__ resid,
    float* __restrict__ outf, unsigned short* __restrict__ outh,
    int M, int N, int K, int relu) {
    __shared__ unsigned short As[64][32];
    __shared__ unsigned short Bs[64][32];
    int tid = threadIdx.x;
    int wave = tid >> 6, lane = tid & 63;
    int lr = lane & 15, quad = lane >> 4;
    int m0 = blockIdx.x * 64, n0 = blockIdx.y * 64;
    int arow = tid >> 2, acol = (tid & 3) * 8;

    floatx4 acc[4];
#pragma unroll
    for (int t = 0; t < 4; ++t)
#pragma unroll
        for (int r = 0; r < 4; ++r) acc[t][r] = 0.0f;

    const size_t a_base = (size_t)(m0 + arow) * K + acol;
    const size_t b_base = (size_t)(n0 + arow) * K + acol;

    for (int k0 = 0; k0 < K; k0 += 32) {
        *(float4*)(&As[arow][acol]) = *(const float4*)(A + a_base + k0);
        *(float4*)(&Bs[arow][acol]) = *(const float4*)(Bt + b_base + k0);
        __syncthreads();
        bf16x8 af = *(const bf16x8*)(&As[16 * wave + lr][quad * 8]);
#pragma unroll
        for (int t = 0; t < 4; ++t) {
            bf16x8 bf = *(const bf16x8*)(&Bs[16 * t + lr][quad * 8]);
            acc[t] = __builtin_amdgcn_mfma_f32_16x16x32_bf16(af, bf, acc[t], 0, 0, 0);
        }
        __syncthreads();
    }

#pragma unroll
    for (int t = 0; t < 4; ++t) {
        int col = n0 + 16 * t + lr;
#pragma unroll
        for (int r = 0; r < 4; ++r) {
            int row = m0 + 16 * wave + quad * 4 + r;
            float v = acc[t][r];
            if (bias)  v += bias[col];
            if (resid) v += resid[(size_t)row * N + col];
            if (relu)  v = fmaxf(v, 0.0f);
            size_t idx = (size_t)row * N + col;
            if (outf) outf[idx] = v;
            else      outh[idx] = f2bf(v);
        }
    }
}

// ---------------------------------------------------------------------------
// V transpose: vb[token][1024] -> vt[bh][dk][s'] with s' = per-64-block
// permutation sigma(u) = 4*(u&15) + (u>>4). This makes the attention PV
// contraction index (j) permuted identically on P-writes and V-reads, so
// P can be written as contiguous ds_write_b64 and V staged as float4.
// ---------------------------------------------------------------------------
__global__ __launch_bounds__(256) void transpose_v(
    const unsigned short* __restrict__ vb, unsigned short* __restrict__ vt) {
    int bh = blockIdx.y;
    int b = bh >> 4, h = bh & 15;
    int s = blockIdx.x * 256 + threadIdx.x;
    size_t inbase = ((size_t)(b * SS + s)) * DDIM + h * 64;
    size_t outbase = (size_t)bh * 64 * SS;
    int sp = (s & ~63) + 4 * (s & 15) + ((s >> 4) & 3);
#pragma unroll
    for (int dk8 = 0; dk8 < 8; ++dk8) {
        uint4 raw = *(const uint4*)(vb + inbase + dk8 * 8);
        const unsigned short* ph = (const unsigned short*)&raw;
#pragma unroll
        for (int i = 0; i < 8; ++i)
            vt[outbase + (size_t)(dk8 * 8 + i) * SS + sp] = ph[i];
    }
}

// ---------------------------------------------------------------------------
// Flash attention, MFMA. One block = (b, h, 64 q-rows); 4 waves x 16 q-rows.
// jt loop over 32 K/V-tiles of 64. S = QK^T via 16x16x32 bf16 MFMA
// (K row-major = B^T layout). Online softmax in C-layout registers
// (row = quad*4+r, col = 16t+lr). P -> per-wave-private LDS (b64 writes via
// sigma permutation) -> A-fragments for PV. V pre-transposed+permuted (vt).
// ---------------------------------------------------------------------------
#define AST 72   // LDS row stride (bf16 elems); breaks 128B bank degeneracy

__global__ __launch_bounds__(256, 4) void attention_mfma(
    const unsigned short* __restrict__ q, const unsigned short* __restrict__ k,
    const unsigned short* __restrict__ vt, unsigned short* __restrict__ ctx) {
    __shared__ unsigned short Qs[64 * AST];
    __shared__ unsigned short Ks[64 * AST];
    __shared__ unsigned short Vs[64 * AST];
    __shared__ unsigned short Ps[64 * AST];

    int tid = threadIdx.x;
    int wave = tid >> 6, lane = tid & 63;
    int lr = lane & 15, quad = lane >> 4;

    int bid = blockIdx.x;
    int qt = bid & 31;
    int bh = bid >> 5;
    int b = bh >> 4, h = bh & 15;
    int q0 = qt * 64;
    size_t qk_base = ((size_t)b * SS) * DDIM + h * 64;
    size_t vt_base = (size_t)bh * 64 * SS;

    // stage Q (pre-scaled by 1/sqrt(dk)=0.125; exact in bf16)
#pragma unroll
    for (int i = 0; i < 2; ++i) {
        int e = i * 256 + tid;
        int r = e >> 3, c8 = (e & 7) * 8;
        uint4 raw = *(const uint4*)(q + qk_base + (size_t)(q0 + r) * DDIM + c8);
        const unsigned short* ph = (const unsigned short*)&raw;
        uint4 outv;
        unsigned short* po = (unsigned short*)&outv;
#pragma unroll
        for (int j = 0; j < 8; ++j) po[j] = f2bf(bf2f(ph[j]) * 0.125f);
        *(uint4*)&Qs[r * AST + c8] = outv;
    }

    floatx4 o[4];
    float m[4], l[4];
#pragma unroll
    for (int t = 0; t < 4; ++t)
#pragma unroll
        for (int r = 0; r < 4; ++r) o[t][r] = 0.0f;
#pragma unroll
    for (int r = 0; r < 4; ++r) { m[r] = -1e30f; l[r] = 0.0f; }

    for (int jt = 0; jt < SS / 64; ++jt) {
        // stage K tile (natural) and V tile (pre-transposed/permuted)
#pragma unroll
        for (int i = 0; i < 2; ++i) {
            int e = i * 256 + tid;
            int r = e >> 3, c8 = (e & 7) * 8;
            *(uint4*)&Ks[r * AST + c8] =
                *(const uint4*)(k + qk_base + (size_t)(jt * 64 + r) * DDIM + c8);
            *(uint4*)&Vs[r * AST + c8] =
                *(const uint4*)(vt + vt_base + (size_t)r * SS + jt * 64 + c8);
        }
        __syncthreads();

        // S-tile: 16 q-rows (this wave) x 64 j
        floatx4 s[4];
#pragma unroll
        for (int t = 0; t < 4; ++t)
#pragma unroll
            for (int r = 0; r < 4; ++r) s[t][r] = 0.0f;
#pragma unroll
        for (int kk = 0; kk < 2; ++kk) {
            bf16x8 af = *(const bf16x8*)&Qs[(16 * wave + lr) * AST + quad * 8 + kk * 32];
#pragma unroll
            for (int t = 0; t < 4; ++t) {
                bf16x8 bfr = *(const bf16x8*)&Ks[(16 * t + lr) * AST + quad * 8 + kk * 32];
                s[t] = __builtin_amdgcn_mfma_f32_16x16x32_bf16(af, bfr, s[t], 0, 0, 0);
            }
        }

        // online softmax + P write (per-wave-private Ps region, no barrier)
#pragma unroll
        for (int r = 0; r < 4; ++r) {
            float rm = fmaxf(fmaxf(s[0][r], s[1][r]), fmaxf(s[2][r], s[3][r]));
            rm = fmaxf(rm, __shfl_xor(rm, 1));
            rm = fmaxf(rm, __shfl_xor(rm, 2));
            rm = fmaxf(rm, __shfl_xor(rm, 4));
            rm = fmaxf(rm, __shfl_xor(rm, 8));
            float mn = fmaxf(m[r], rm);
            float al = __expf(m[r] - mn);
            m[r] = mn;
            float p0 = __expf(s[0][r] - mn);
            float p1 = __expf(s[1][r] - mn);
            float p2 = __expf(s[2][r] - mn);
            float p3 = __expf(s[3][r] - mn);
            float rs = p0 + p1 + p2 + p3;
            rs += __shfl_xor(rs, 1);
            rs += __shfl_xor(rs, 2);
            rs += __shfl_xor(rs, 4);
            rs += __shfl_xor(rs, 8);
            l[r] = l[r] * al + rs;
#pragma unroll
            for (int t = 0; t < 4; ++t) o[t][r] *= al;
            // P[m=quad*4+r][j=16t+lr] -> permuted col sigma(j)=4*lr+t
            ushort4 pw;
            pw.x = f2bf(p0); pw.y = f2bf(p1); pw.z = f2bf(p2); pw.w = f2bf(p3);
            *(ushort4*)&Ps[(wave * 16 + quad * 4 + r) * AST + 4 * lr] = pw;
        }

        // PV: O += P @ V   (contraction over permuted j; Vs rows = dk)
#pragma unroll
        for (int kk = 0; kk < 2; ++kk) {
            bf16x8 pf = *(const bf16x8*)&Ps[(16 * wave + lr) * AST + quad * 8 + kk * 32];
#pragma unroll
            for (int t = 0; t < 4; ++t) {
                bf16x8 vf = *(const bf16x8*)&Vs[(16 * t + lr) * AST + quad * 8 + kk * 32];
                o[t] = __builtin_amdgcn_mfma_f32_16x16x32_bf16(pf, vf, o[t], 0, 0, 0);
            }
        }
        __syncthreads();   // before next iteration overwrites Ks/Vs
    }

    // epilogue: O /= l, write ctx
#pragma unroll
    for (int r = 0; r < 4; ++r) {
        float inv = 1.0f / l[r];
        int row = q0 + 16 * wave + quad * 4 + r;
        size_t base = ((size_t)(b * SS + row)) * DDIM + h * 64;
#pragma unroll
        for (int t = 0; t < 4; ++t)
            ctx[base + 16 * t + lr] = f2bf(o[t][r] * inv);
    }
}

// ---------------------------------------------------------------------------
extern "C" void kernel_launch(void* const* d_in, const int* in_sizes, int n_in,
                              void* d_out, int out_size, void* d_ws, size_t ws_size,
                              hipStream_t stream) {
    const float* x     = (const float*)d_in[0];
    const float* Wq    = (const float*)d_in[1];
    const float* Wk    = (const float*)d_in[2];
    const float* Wv    = (const float*)d_in[3];
    const float* Wo    = (const float*)d_in[4];
    const float* ln1g  = (const float*)d_in[5];
    const float* ln1b  = (const float*)d_in[6];
    const float* fc1w  = (const float*)d_in[7];
    const float* fc1b  = (const float*)d_in[8];
    const float* fc2w  = (const float*)d_in[9];
    const float* fc2b  = (const float*)d_in[10];
    const float* ln2g  = (const float*)d_in[11];
    const float* ln2b  = (const float*)d_in[12];
    float* out = (float*)d_out;

    // workspace layout (peak 80MB, same as round 0):
    //  0-16  : weights (bf16, transposed)
    // 16-32  : xn (LN1 out) -> reused as ctx
    // 32-48  : qb -> reused as hn
    // 48-64  : vb (V-proj out, dies after transpose_v) -> kb -> h1 lower half
    // 64-80  : vt (dies after attention) -> h1 upper half
    char* ws = (char*)d_ws;
    const size_t MB = 1024 * 1024;
    unsigned short* wqT  = (unsigned short*)(ws + 0 * MB);
    unsigned short* wkT  = (unsigned short*)(ws + 2 * MB);
    unsigned short* wvT  = (unsigned short*)(ws + 4 * MB);
    unsigned short* woT  = (unsigned short*)(ws + 6 * MB);
    unsigned short* fc1T = (unsigned short*)(ws + 8 * MB);
    unsigned short* fc2T = (unsigned short*)(ws + 12 * MB);
    unsigned short* xn   = (unsigned short*)(ws + 16 * MB);
    unsigned short* qb   = (unsigned short*)(ws + 32 * MB);
    unsigned short* kb   = (unsigned short*)(ws + 48 * MB);
    unsigned short* vb   = kb;                               // time-shared
    unsigned short* vt   = (unsigned short*)(ws + 64 * MB);
    unsigned short* ctx  = xn;
    unsigned short* hn   = qb;
    unsigned short* h1   = kb;                               // 48-80MB

    dim3 blk(256);

    transpose_to_bf16<<<dim3(16, 16), blk, 0, stream>>>(Wq, wqT, 1024, 1024);
    transpose_to_bf16<<<dim3(16, 16), blk, 0, stream>>>(Wk, wkT, 1024, 1024);
    transpose_to_bf16<<<dim3(16, 16), blk, 0, stream>>>(Wv, wvT, 1024, 1024);
    transpose_to_bf16<<<dim3(16, 16), blk, 0, stream>>>(Wo, woT, 1024, 1024);
    transpose_to_bf16<<<dim3(16, 32), blk, 0, stream>>>(fc1w, fc1T, 1024, 2048);
    transpose_to_bf16<<<dim3(32, 16), blk, 0, stream>>>(fc2w, fc2T, 2048, 1024);

    layernorm_bf16<<<NTOK, blk, 0, stream>>>(x, ln1g, ln1b, xn, 1e-5f);

    // V first so vb can die before K-gemm reuses its region
    gemm_bt<<<dim3(128, 16), blk, 0, stream>>>(xn, wvT, nullptr, nullptr, nullptr, vb, NTOK, 1024, 1024, 0);
    transpose_v<<<dim3(8, 64), blk, 0, stream>>>(vb, vt);
    gemm_bt<<<dim3(128, 16), blk, 0, stream>>>(xn, wqT, nullptr, nullptr, nullptr, qb, NTOK, 1024, 1024, 0);
    gemm_bt<<<dim3(128, 16), blk, 0, stream>>>(xn, wkT, nullptr, nullptr, nullptr, kb, NTOK, 1024, 1024, 0);

    attention_mfma<<<2048, blk, 0, stream>>>(qb, kb, vt, ctx);

    gemm_bt<<<dim3(128, 16), blk, 0, stream>>>(ctx, woT, nullptr, x, out, nullptr, NTOK, 1024, 1024, 0);
    layernorm_bf16<<<NTOK, blk, 0, stream>>>(out, ln2g, ln2b, hn, 1e-6f);
    gemm_bt<<<dim3(128, 32), blk, 0, stream>>>(hn, fc1T, fc1b, nullptr, nullptr, h1, NTOK, 2048, 1024, 1);
    gemm_bt<<<dim3(128, 16), blk, 0, stream>>>(h1, fc2T, fc2b, out, out, nullptr, NTOK, 1024, 2048, 0);
}

// Round 3
// 668.857 us; speedup vs baseline: 6.6870x; 1.0444x over previous
//
#include <hip/hip_runtime.h>

// Problem constants
#define BB   4
#define SS   2048
#define DDIM 1024
#define HH   16
#define DKK  64
#define FFF  2048
#define NTOK (BB * SS)   // 8192

typedef __bf16 bf16x8 __attribute__((ext_vector_type(8)));
typedef float floatx4 __attribute__((ext_vector_type(4)));

__device__ __forceinline__ unsigned short f2bf(float f) {
    union { float f; unsigned u; } v; v.f = f;
    unsigned r = v.u + 0x7fffu + ((v.u >> 16) & 1u);   // RNE
    return (unsigned short)(r >> 16);
}
__device__ __forceinline__ float bf2f(unsigned short h) {
    union { unsigned u; float f; } v; v.u = ((unsigned)h) << 16;
    return v.f;
}

// async 16B/lane global->LDS (lds dest = wave-uniform base + lane*16)
__device__ __forceinline__ void async_copy16(const unsigned short* g, unsigned short* l) {
    __builtin_amdgcn_global_load_lds(
        (const __attribute__((address_space(1))) void*)g,
        (__attribute__((address_space(3))) void*)l, 16, 0, 0);
}

// ---------------------------------------------------------------------------
// Transpose fp32 W[K][N] -> bf16 Wt[N][K]
// ---------------------------------------------------------------------------
__global__ __launch_bounds__(256) void transpose_to_bf16(
    const float* __restrict__ W, unsigned short* __restrict__ Wt, int K, int N) {
    __shared__ float tile[64][65];
    int k0 = blockIdx.x * 64, n0 = blockIdx.y * 64;
    int tid = threadIdx.x;
#pragma unroll
    for (int i = 0; i < 16; ++i) {
        int e = i * 256 + tid;
        int r = e >> 6, c = e & 63;
        tile[r][c] = W[(size_t)(k0 + r) * N + (n0 + c)];
    }
    __syncthreads();
#pragma unroll
    for (int i = 0; i < 16; ++i) {
        int e = i * 256 + tid;
        int r = e >> 6, c = e & 63;
        Wt[(size_t)(n0 + r) * K + (k0 + c)] = f2bf(tile[c][r]);
    }
}

// ---------------------------------------------------------------------------
// LayerNorm: fp32 in -> bf16 out
// ---------------------------------------------------------------------------
__device__ __forceinline__ float block_sum256(float s) {
#pragma unroll
    for (int o = 32; o > 0; o >>= 1) s += __shfl_xor(s, o);
    __shared__ float partial[4];
    int w = threadIdx.x >> 6;
    __syncthreads();
    if ((threadIdx.x & 63) == 0) partial[w] = s;
    __syncthreads();
    return partial[0] + partial[1] + partial[2] + partial[3];
}

__global__ __launch_bounds__(256) void layernorm_bf16(
    const float* __restrict__ x, const float* __restrict__ g,
    const float* __restrict__ b, unsigned short* __restrict__ out, float eps) {
    size_t row = blockIdx.x;
    const float* xr = x + row * DDIM;
    int tid = threadIdx.x;
    float4 v = *(const float4*)(xr + tid * 4);
    float mu = block_sum256(v.x + v.y + v.z + v.w) * (1.0f / DDIM);
    float dx = v.x - mu, dy = v.y - mu, dz = v.z - mu, dw = v.w - mu;
    float var = block_sum256(dx * dx + dy * dy + dz * dz + dw * dw) * (1.0f / DDIM);
    float rstd = rsqrtf(var + eps);
    int c = tid * 4;
    unsigned short* o = out + row * DDIM + c;
    o[0] = f2bf(dx * rstd * g[c + 0] + b[c + 0]);
    o[1] = f2bf(dy * rstd * g[c + 1] + b[c + 1]);
    o[2] = f2bf(dz * rstd * g[c + 2] + b[c + 2]);
    o[3] = f2bf(dw * rstd * g[c + 3] + b[c + 3]);
}

// ---------------------------------------------------------------------------
// m97-style 128x128 bf16 MFMA GEMM. C = A[MxK] @ Bt[NxK]^T (+bias+resid,relu)
// 4 waves in 2x2 over the tile; each wave: 4x4 subtiles of 16x16, BK=32.
// Staging via global_load_lds width=16 (LDS layout row-major [128][32],
// NO padding — required by the lane-ordered LDS landing).
// ---------------------------------------------------------------------------
__global__ __launch_bounds__(256) void gemm_bt128(
    const unsigned short* __restrict__ A, const unsigned short* __restrict__ Bt,
    const float* __restrict__ bias, const float* __restrict__ resid,
    float* __restrict__ outf, unsigned short* __restrict__ outh,
    int M, int N, int K, int relu) {
    __shared__ unsigned short As[128 * 32];
    __shared__ unsigned short Bs[128 * 32];
    int tid = threadIdx.x;
    int wave = tid >> 6, lane = tid & 63;
    int lr = lane & 15, quad = lane >> 4;
    int m0 = blockIdx.x * 128, n0 = blockIdx.y * 128;
    int wm = (wave >> 1) * 64, wn = (wave & 1) * 64;

    floatx4 acc[4][4];
#pragma unroll
    for (int i = 0; i < 4; ++i)
#pragma unroll
        for (int t = 0; t < 4; ++t)
#pragma unroll
            for (int r = 0; r < 4; ++r) acc[i][t][r] = 0.0f;

    // staging: wave w covers rows 32w..32w+31 of each 128x32 tile;
    // lane i -> row 32w + 16j + (i>>2), col (i&3)*8  (j = 0,1)
    int srow = 32 * wave + (lane >> 2);
    int scol = (lane & 3) * 8;
    const unsigned short* ag0 = A  + (size_t)(m0 + srow) * K + scol;
    const unsigned short* ag1 = A  + (size_t)(m0 + srow + 16) * K + scol;
    const unsigned short* bg0 = Bt + (size_t)(n0 + srow) * K + scol;
    const unsigned short* bg1 = Bt + (size_t)(n0 + srow + 16) * K + scol;
    unsigned short* al0 = &As[(32 * wave) * 32];
    unsigned short* al1 = &As[(32 * wave + 16) * 32];
    unsigned short* bl0 = &Bs[(32 * wave) * 32];
    unsigned short* bl1 = &Bs[(32 * wave + 16) * 32];

    for (int k0 = 0; k0 < K; k0 += 32) {
        async_copy16(ag0 + k0, al0);
        async_copy16(ag1 + k0, al1);
        async_copy16(bg0 + k0, bl0);
        async_copy16(bg1 + k0, bl1);
        __syncthreads();

        bf16x8 af[4], bfr[4];
#pragma unroll
        for (int i = 0; i < 4; ++i)
            af[i] = *(const bf16x8*)&As[(wm + 16 * i + lr) * 32 + quad * 8];
#pragma unroll
        for (int t = 0; t < 4; ++t)
            bfr[t] = *(const bf16x8*)&Bs[(wn + 16 * t + lr) * 32 + quad * 8];
#pragma unroll
        for (int i = 0; i < 4; ++i)
#pragma unroll
            for (int t = 0; t < 4; ++t)
                acc[i][t] = __builtin_amdgcn_mfma_f32_16x16x32_bf16(af[i], bfr[t], acc[i][t], 0, 0, 0);
        __syncthreads();
    }

#pragma unroll
    for (int i = 0; i < 4; ++i) {
#pragma unroll
        for (int t = 0; t < 4; ++t) {
            int col = n0 + wn + 16 * t + lr;
#pragma unroll
            for (int r = 0; r < 4; ++r) {
                int row = m0 + wm + 16 * i + quad * 4 + r;
                float v = acc[i][t][r];
                if (bias)  v += bias[col];
                if (resid) v += resid[(size_t)row * N + col];
                if (relu)  v = fmaxf(v, 0.0f);
                size_t idx = (size_t)row * N + col;
                if (outf) outf[idx] = v;
                else      outh[idx] = f2bf(v);
            }
        }
    }
}

// ---------------------------------------------------------------------------
// V transpose: vb[token][1024] -> vt[bh][dk][s'] with per-64-block
// permutation sigma(u) = 4*(u&15) + (u>>4)  (matches attention P-writes).
// ---------------------------------------------------------------------------
__global__ __launch_bounds__(256) void transpose_v(
    const unsigned short* __restrict__ vb, unsigned short* __restrict__ vt) {
    int bh = blockIdx.y;
    int b = bh >> 4, h = bh & 15;
    int s = blockIdx.x * 256 + threadIdx.x;
    size_t inbase = ((size_t)(b * SS + s)) * DDIM + h * 64;
    size_t outbase = (size_t)bh * 64 * SS;
    int sp = (s & ~63) + 4 * (s & 15) + ((s >> 4) & 3);
#pragma unroll
    for (int dk8 = 0; dk8 < 8; ++dk8) {
        uint4 raw = *(const uint4*)(vb + inbase + dk8 * 8);
        const unsigned short* ph = (const unsigned short*)&raw;
#pragma unroll
        for (int i = 0; i < 8; ++i)
            vt[outbase + (size_t)(dk8 * 8 + i) * SS + sp] = ph[i];
    }
}

// ---------------------------------------------------------------------------
// Flash attention, MFMA (unchanged from round 1).
// ---------------------------------------------------------------------------
#define AST 72

__global__ __launch_bounds__(256, 4) void attention_mfma(
    const unsigned short* __restrict__ q, const unsigned short* __restrict__ k,
    const unsigned short* __restrict__ vt, unsigned short* __restrict__ ctx) {
    __shared__ unsigned short Qs[64 * AST];
    __shared__ unsigned short Ks[64 * AST];
    __shared__ unsigned short Vs[64 * AST];
    __shared__ unsigned short Ps[64 * AST];

    int tid = threadIdx.x;
    int wave = tid >> 6, lane = tid & 63;
    int lr = lane & 15, quad = lane >> 4;

    int bid = blockIdx.x;
    int qt = bid & 31;
    int bh = bid >> 5;
    int b = bh >> 4, h = bh & 15;
    int q0 = qt * 64;
    size_t qk_base = ((size_t)b * SS) * DDIM + h * 64;
    size_t vt_base = (size_t)bh * 64 * SS;

#pragma unroll
    for (int i = 0; i < 2; ++i) {
        int e = i * 256 + tid;
        int r = e >> 3, c8 = (e & 7) * 8;
        uint4 raw = *(const uint4*)(q + qk_base + (size_t)(q0 + r) * DDIM + c8);
        const unsigned short* ph = (const unsigned short*)&raw;
        uint4 outv;
        unsigned short* po = (unsigned short*)&outv;
#pragma unroll
        for (int j = 0; j < 8; ++j) po[j] = f2bf(bf2f(ph[j]) * 0.125f);
        *(uint4*)&Qs[r * AST + c8] = outv;
    }

    floatx4 o[4];
    float m[4], l[4];
#pragma unroll
    for (int t = 0; t < 4; ++t)
#pragma unroll
        for (int r = 0; r < 4; ++r) o[t][r] = 0.0f;
#pragma unroll
    for (int r = 0; r < 4; ++r) { m[r] = -1e30f; l[r] = 0.0f; }

    for (int jt = 0; jt < SS / 64; ++jt) {
#pragma unroll
        for (int i = 0; i < 2; ++i) {
            int e = i * 256 + tid;
            int r = e >> 3, c8 = (e & 7) * 8;
            *(uint4*)&Ks[r * AST + c8] =
                *(const uint4*)(k + qk_base + (size_t)(jt * 64 + r) * DDIM + c8);
            *(uint4*)&Vs[r * AST + c8] =
                *(const uint4*)(vt + vt_base + (size_t)r * SS + jt * 64 + c8);
        }
        __syncthreads();

        floatx4 s[4];
#pragma unroll
        for (int t = 0; t < 4; ++t)
#pragma unroll
            for (int r = 0; r < 4; ++r) s[t][r] = 0.0f;
#pragma unroll
        for (int kk = 0; kk < 2; ++kk) {
            bf16x8 af = *(const bf16x8*)&Qs[(16 * wave + lr) * AST + quad * 8 + kk * 32];
#pragma unroll
            for (int t = 0; t < 4; ++t) {
                bf16x8 bfr = *(const bf16x8*)&Ks[(16 * t + lr) * AST + quad * 8 + kk * 32];
                s[t] = __builtin_amdgcn_mfma_f32_16x16x32_bf16(af, bfr, s[t], 0, 0, 0);
            }
        }

#pragma unroll
        for (int r = 0; r < 4; ++r) {
            float rm = fmaxf(fmaxf(s[0][r], s[1][r]), fmaxf(s[2][r], s[3][r]));
            rm = fmaxf(rm, __shfl_xor(rm, 1));
            rm = fmaxf(rm, __shfl_xor(rm, 2));
            rm = fmaxf(rm, __shfl_xor(rm, 4));
            rm = fmaxf(rm, __shfl_xor(rm, 8));
            float mn = fmaxf(m[r], rm);
            float al = __expf(m[r] - mn);
            m[r] = mn;
            float p0 = __expf(s[0][r] - mn);
            float p1 = __expf(s[1][r] - mn);
            float p2 = __expf(s[2][r] - mn);
            float p3 = __expf(s[3][r] - mn);
            float rs = p0 + p1 + p2 + p3;
            rs += __shfl_xor(rs, 1);
            rs += __shfl_xor(rs, 2);
            rs += __shfl_xor(rs, 4);
            rs += __shfl_xor(rs, 8);
            l[r] = l[r] * al + rs;
#pragma unroll
            for (int t = 0; t < 4; ++t) o[t][r] *= al;
            ushort4 pw;
            pw.x = f2bf(p0); pw.y = f2bf(p1); pw.z = f2bf(p2); pw.w = f2bf(p3);
            *(ushort4*)&Ps[(wave * 16 + quad * 4 + r) * AST + 4 * lr] = pw;
        }

#pragma unroll
        for (int kk = 0; kk < 2; ++kk) {
            bf16x8 pf = *(const bf16x8*)&Ps[(16 * wave + lr) * AST + quad * 8 + kk * 32];
#pragma unroll
            for (int t = 0; t < 4; ++t) {
                bf16x8 vf = *(const bf16x8*)&Vs[(16 * t + lr) * AST + quad * 8 + kk * 32];
                o[t] = __builtin_amdgcn_mfma_f32_16x16x32_bf16(pf, vf, o[t], 0, 0, 0);
            }
        }
        __syncthreads();
    }

#pragma unroll
    for (int r = 0; r < 4; ++r) {
        float inv = 1.0f / l[r];
        int row = q0 + 16 * wave + quad * 4 + r;
        size_t base = ((size_t)(b * SS + row)) * DDIM + h * 64;
#pragma unroll
        for (int t = 0; t < 4; ++t)
            ctx[base + 16 * t + lr] = f2bf(o[t][r] * inv);
    }
}

// ---------------------------------------------------------------------------
extern "C" void kernel_launch(void* const* d_in, const int* in_sizes, int n_in,
                              void* d_out, int out_size, void* d_ws, size_t ws_size,
                              hipStream_t stream) {
    const float* x     = (const float*)d_in[0];
    const float* Wq    = (const float*)d_in[1];
    const float* Wk    = (const float*)d_in[2];
    const float* Wv    = (const float*)d_in[3];
    const float* Wo    = (const float*)d_in[4];
    const float* ln1g  = (const float*)d_in[5];
    const float* ln1b  = (const float*)d_in[6];
    const float* fc1w  = (const float*)d_in[7];
    const float* fc1b  = (const float*)d_in[8];
    const float* fc2w  = (const float*)d_in[9];
    const float* fc2b  = (const float*)d_in[10];
    const float* ln2g  = (const float*)d_in[11];
    const float* ln2b  = (const float*)d_in[12];
    float* out = (float*)d_out;

    char* ws = (char*)d_ws;
    const size_t MB = 1024 * 1024;
    unsigned short* wqT  = (unsigned short*)(ws + 0 * MB);
    unsigned short* wkT  = (unsigned short*)(ws + 2 * MB);
    unsigned short* wvT  = (unsigned short*)(ws + 4 * MB);
    unsigned short* woT  = (unsigned short*)(ws + 6 * MB);
    unsigned short* fc1T = (unsigned short*)(ws + 8 * MB);
    unsigned short* fc2T = (unsigned short*)(ws + 12 * MB);
    unsigned short* xn   = (unsigned short*)(ws + 16 * MB);
    unsigned short* qb   = (unsigned short*)(ws + 32 * MB);
    unsigned short* kb   = (unsigned short*)(ws + 48 * MB);
    unsigned short* vb   = kb;                               // time-shared
    unsigned short* vt   = (unsigned short*)(ws + 64 * MB);
    unsigned short* ctx  = xn;
    unsigned short* hn   = qb;
    unsigned short* h1   = kb;                               // 48-80MB

    dim3 blk(256);

    transpose_to_bf16<<<dim3(16, 16), blk, 0, stream>>>(Wq, wqT, 1024, 1024);
    transpose_to_bf16<<<dim3(16, 16), blk, 0, stream>>>(Wk, wkT, 1024, 1024);
    transpose_to_bf16<<<dim3(16, 16), blk, 0, stream>>>(Wv, wvT, 1024, 1024);
    transpose_to_bf16<<<dim3(16, 16), blk, 0, stream>>>(Wo, woT, 1024, 1024);
    transpose_to_bf16<<<dim3(16, 32), blk, 0, stream>>>(fc1w, fc1T, 1024, 2048);
    transpose_to_bf16<<<dim3(32, 16), blk, 0, stream>>>(fc2w, fc2T, 2048, 1024);

    layernorm_bf16<<<NTOK, blk, 0, stream>>>(x, ln1g, ln1b, xn, 1e-5f);

    // V first so vb can die before K-gemm reuses its region
    gemm_bt128<<<dim3(64, 8), blk, 0, stream>>>(xn, wvT, nullptr, nullptr, nullptr, vb, NTOK, 1024, 1024, 0);
    transpose_v<<<dim3(8, 64), blk, 0, stream>>>(vb, vt);
    gemm_bt128<<<dim3(64, 8), blk, 0, stream>>>(xn, wqT, nullptr, nullptr, nullptr, qb, NTOK, 1024, 1024, 0);
    gemm_bt128<<<dim3(64, 8), blk, 0, stream>>>(xn, wkT, nullptr, nullptr, nullptr, kb, NTOK, 1024, 1024, 0);

    attention_mfma<<<2048, blk, 0, stream>>>(qb, kb, vt, ctx);

    gemm_bt128<<<dim3(64, 8), blk, 0, stream>>>(ctx, woT, nullptr, x, out, nullptr, NTOK, 1024, 1024, 0);
    layernorm_bf16<<<NTOK, blk, 0, stream>>>(out, ln2g, ln2b, hn, 1e-6f);
    gemm_bt128<<<dim3(64, 16), blk, 0, stream>>>(hn, fc1T, fc1b, nullptr, nullptr, h1, NTOK, 2048, 1024, 1);
    gemm_bt128<<<dim3(64, 8), blk, 0, stream>>>(h1, fc2T, fc2b, out, out, nullptr, NTOK, 1024, 2048, 0);
}